// Round 1
// baseline (814.705 us; speedup 1.0000x reference)
//
#include <hip/hip_runtime.h>

typedef __bf16 bf16;
typedef bf16 bf16x8 __attribute__((ext_vector_type(8)));
typedef bf16 bf16x4v __attribute__((ext_vector_type(4)));
typedef bf16 bf16x2v __attribute__((ext_vector_type(2)));
typedef float f32x4 __attribute__((ext_vector_type(4)));

#define EPS 1e-6f

// Per-wave LDS region (7488 B), barrier-free (each wave touches only its own):
//   bytes 0..7424 : feats [16][232] bf16  (phase A out, GEMM1 A-operand)
//                   then reused: Hs [16][72] bf16, then gateb [16][232] bf16
//   bytes 7424..7488 : srow [16] f32
// 4 waves * 7488 = 29952 B/block -> LDS allows 5 blocks/CU; launch_bounds(256,5)
// caps VGPR at 102 so 5 blocks (20 waves/CU) can be resident.
//
// Row ownership in phase A / epilogue: row i = 4p + q is owned by the 16 lanes
// with quad q (c = 0..15). 128 = 16*8 scalars, 192 = 16*12 vec3 floats (4 whole
// groups of 3 per lane), 160 = 16*10 vec5 floats (2 whole groups of 5 per lane)
// -> all loads are lane-contiguous float4/float2, all reductions are 4-step
// xor-reduces within 16 lanes (DPP-class), all gate lookups are lane-local.

struct XR { float4 s0, s1, t0, t1, t2; float2 u0, u1, u2, u3, u4; };
struct XE { float4 a0, a1, a2; float2 b0, b1, b2, b3, b4; };

__device__ __forceinline__ XR ldrow(const float* __restrict__ xr, int c) {
    XR r;
    r.s0 = *(const float4*)(xr + 8 * c);
    r.s1 = *(const float4*)(xr + 8 * c + 4);
    const float* tp = xr + 128 + 12 * c;        // bytes: 512 + 48c, 16B aligned
    r.t0 = *(const float4*)(tp);
    r.t1 = *(const float4*)(tp + 4);
    r.t2 = *(const float4*)(tp + 8);
    const float* up = xr + 320 + 10 * c;        // bytes: 1280 + 40c, 8B aligned
    r.u0 = *(const float2*)(up);
    r.u1 = *(const float2*)(up + 2);
    r.u2 = *(const float2*)(up + 4);
    r.u3 = *(const float2*)(up + 6);
    r.u4 = *(const float2*)(up + 8);
    return r;
}

__device__ __forceinline__ XE ldxe(const float* __restrict__ xr, int c) {
    XE r;
    const float* tp = xr + 128 + 12 * c;
    r.a0 = *(const float4*)(tp);
    r.a1 = *(const float4*)(tp + 4);
    r.a2 = *(const float4*)(tp + 8);
    const float* up = xr + 320 + 10 * c;
    r.b0 = *(const float2*)(up);
    r.b1 = *(const float2*)(up + 2);
    r.b2 = *(const float2*)(up + 4);
    r.b3 = *(const float2*)(up + 6);
    r.b4 = *(const float2*)(up + 8);
    return r;
}

__global__ __launch_bounds__(256, 5) void fused(
    const float* __restrict__ x,
    const float* __restrict__ b1v, const float* __restrict__ b2v,
    const float* __restrict__ aw,  const float* __restrict__ ab,
    const bf16* __restrict__ W1b,  const bf16* __restrict__ W2b,
    float* __restrict__ out)
{
    __shared__ unsigned char smem[4 * 7488];
    const int tid = threadIdx.x;
    const int wv  = tid >> 6;
    const int l   = tid & 63;
    const int q   = l >> 4;     // quad 0..3
    const int c   = l & 15;     // lane-in-16
    unsigned char* reg = smem + wv * 7488;
    bf16*  feats = (bf16*)reg;             // [16][232]
    bf16*  Hs    = (bf16*)reg;             // [16][72]   (overlays feats after A-frag read)
    bf16*  gateb = (bf16*)reg;             // [16][232]  (overlays Hs after H-frag read)
    float* srow  = (float*)(reg + 7424);   // [16]
    const int r0w = blockIdx.x * 64 + wv * 16;
    const float* xw = x + (size_t)r0w * 480;

    // ---------------- Phase A: wide lane-local loads, 16-lane DPP reductions ----------------
    float cen[4][8];            // centered scalars, kept fp32 for the epilogue
    XR cur = ldrow(xw + q * 480, c);
    #pragma unroll
    for (int p = 0; p < 4; ++p) {
        XR nxt;
        if (p < 3) nxt = ldrow(xw + (4 * (p + 1) + q) * 480, c);  // prefetch next row-group
        const int i = 4 * p + q;
        float vs[8] = {cur.s0.x, cur.s0.y, cur.s0.z, cur.s0.w,
                       cur.s1.x, cur.s1.y, cur.s1.z, cur.s1.w};
        float S1 = 0.f, SS = 0.f;
        #pragma unroll
        for (int j = 0; j < 8; ++j) { S1 += vs[j]; SS = fmaf(vs[j], vs[j], SS); }
        // 4 whole 3-groups per lane (cols 128+12c .. 128+12c+11)
        const float g0 = cur.t0.x*cur.t0.x + cur.t0.y*cur.t0.y + cur.t0.z*cur.t0.z;
        const float g1 = cur.t0.w*cur.t0.w + cur.t1.x*cur.t1.x + cur.t1.y*cur.t1.y;
        const float g2 = cur.t1.z*cur.t1.z + cur.t1.w*cur.t1.w + cur.t2.x*cur.t2.x;
        const float g3 = cur.t2.y*cur.t2.y + cur.t2.z*cur.t2.z + cur.t2.w*cur.t2.w;
        // 2 whole 5-groups per lane (cols 320+10c .. 320+10c+9)
        const float gA = cur.u0.x*cur.u0.x + cur.u0.y*cur.u0.y + cur.u1.x*cur.u1.x
                       + cur.u1.y*cur.u1.y + cur.u2.x*cur.u2.x;
        const float gB = cur.u2.y*cur.u2.y + cur.u3.x*cur.u3.x + cur.u3.y*cur.u3.y
                       + cur.u4.x*cur.u4.x + cur.u4.y*cur.u4.y;
        // per-lane contribution to sum of rms^2 (incl. the EPS inside each rms^2)
        float Qp = (g0 + g1 + g2 + g3) * (1.f / 3.f) + (gA + gB) * 0.2f + 6.f * EPS;
        // one combined 16-lane xor-reduce (masks 1,2,4,8 -> stays in 16-lane groups)
        #pragma unroll
        for (int m = 1; m < 16; m <<= 1) {
            S1 += __shfl_xor(S1, m);
            SS += __shfl_xor(SS, m);
            Qp += __shfl_xor(Qp, m);
        }
        const float mean = S1 * (1.f / 128.f);
        // sum(cen^2) = SS - S1^2/128 ; ms = (sum(cen^2) + sum(rms^2)) / 224
        const float sr = rsqrtf((SS - S1 * mean + Qp) * (1.f / 224.f) + EPS);
        if (c == 0) srow[i] = sr;
        bf16x8 fs;
        #pragma unroll
        for (int j = 0; j < 8; ++j) {
            const float cj = vs[j] - mean;
            cen[p][j] = cj;
            fs[j] = (bf16)cj;
        }
        *(bf16x8*)(feats + i * 232 + 8 * c) = fs;          // b128, aligned
        bf16x4v f3;
        f3[0] = (bf16)sqrtf(g0 * (1.f / 3.f) + EPS);
        f3[1] = (bf16)sqrtf(g1 * (1.f / 3.f) + EPS);
        f3[2] = (bf16)sqrtf(g2 * (1.f / 3.f) + EPS);
        f3[3] = (bf16)sqrtf(g3 * (1.f / 3.f) + EPS);
        *(bf16x4v*)(feats + i * 232 + 128 + 4 * c) = f3;   // b64, aligned
        bf16x2v f5;
        f5[0] = (bf16)sqrtf(gA * 0.2f + EPS);
        f5[1] = (bf16)sqrtf(gB * 0.2f + EPS);
        *(bf16x2v*)(feats + i * 232 + 192 + 2 * c) = f5;   // b32, aligned
        if (p < 3) cur = nxt;
    }
    __builtin_amdgcn_wave_barrier();

    // ---------------- GEMM1: H = silu(srow*(feats @ W1^T) + b1) ----------------
    bf16x8 af[7];
    {
        const bf16* frow = feats + c * 232;
        #pragma unroll
        for (int ks = 0; ks < 7; ++ks)
            af[ks] = *(const bf16x8*)(frow + ks * 32 + q * 8);
    }
    float sr4[4];
    #pragma unroll
    for (int r = 0; r < 4; ++r) sr4[r] = srow[q * 4 + r];
    __builtin_amdgcn_wave_barrier();   // af in regs; feats region may be overwritten below
    #pragma unroll
    for (int t = 0; t < 4; ++t) {
        f32x4 acc = {0.f, 0.f, 0.f, 0.f};
        const int n = t * 16 + c;
        const bf16* wrow = W1b + n * 224 + q * 8;  // B[k][n] = W1[n][k]
        #pragma unroll
        for (int ks = 0; ks < 7; ++ks)
            acc = __builtin_amdgcn_mfma_f32_16x16x32_bf16(
                      af[ks], *(const bf16x8*)(wrow + ks * 32), acc, 0, 0, 0);
        float bb = 0.f;
        if (n < 56) bb = b1v[n];
        #pragma unroll
        for (int r = 0; r < 4; ++r) {
            const int row = q * 4 + r;            // C: col=c, row=q*4+r
            const float z = acc[r] * sr4[r] + bb;
            float hv = 0.f;
            if (n < 56) hv = z / (1.f + __expf(-z));   // silu; zero pad cols 56..63
            Hs[row * 72 + n] = (bf16)hv;
        }
    }
    __builtin_amdgcn_wave_barrier();

    // ---------------- GEMM2: gate = sigmoid(H @ W2^T + b2) * aff_w ----------------
    const bf16x8 ha0 = *(const bf16x8*)(Hs + c * 72 + q * 8);
    const bf16x8 ha1 = *(const bf16x8*)(Hs + c * 72 + 32 + q * 8);
    // prefetch epilogue operands under GEMM2's exp-heavy loop
    const float4 abA = *(const float4*)(ab + 8 * c);
    const float4 abB = *(const float4*)(ab + 8 * c + 4);
    XE xc = ldxe(xw + q * 480, c);     // first epilogue row-group (L2-hot)
    __builtin_amdgcn_wave_barrier();   // ha in regs; Hs region may be overwritten below
    #pragma unroll
    for (int t = 0; t < 14; ++t) {
        f32x4 acc = {0.f, 0.f, 0.f, 0.f};
        const int nn = t * 16 + c;
        const bf16* wrow = W2b + nn * 64 + q * 8;  // B[k][n] = W2[n][k], k-padded to 64 (zeros)
        acc = __builtin_amdgcn_mfma_f32_16x16x32_bf16(ha0, *(const bf16x8*)(wrow),      acc, 0, 0, 0);
        acc = __builtin_amdgcn_mfma_f32_16x16x32_bf16(ha1, *(const bf16x8*)(wrow + 32), acc, 0, 0, 0);
        const float bb = b2v[nn];
        const float a  = aw[nn];
        #pragma unroll
        for (int r = 0; r < 4; ++r) {
            const int row = q * 4 + r;
            const float g = a / (1.f + __expf(-(acc[r] + bb)));
            gateb[row * 232 + nn] = (bf16)g;
        }
    }
    __builtin_amdgcn_wave_barrier();

    // ---------------- Epilogue: wide lane-local stores, gate lookups lane-local ----------------
    #pragma unroll
    for (int p = 0; p < 4; ++p) {
        const int i = 4 * p + q;
        XE xn;
        if (p < 3) xn = ldxe(xw + (i + 4) * 480, c);   // prefetch next row-group
        const bf16x8  gs = *(const bf16x8*)(gateb + i * 232 + 8 * c);
        const bf16x4v g3 = *(const bf16x4v*)(gateb + i * 232 + 128 + 4 * c);
        const bf16x2v g5 = *(const bf16x2v*)(gateb + i * 232 + 192 + 2 * c);
        float* ob = out + (size_t)(r0w + i) * 480;
        float4 o0, o1;
        o0.x = fmaf(cen[p][0], (float)gs[0], abA.x);
        o0.y = fmaf(cen[p][1], (float)gs[1], abA.y);
        o0.z = fmaf(cen[p][2], (float)gs[2], abA.z);
        o0.w = fmaf(cen[p][3], (float)gs[3], abA.w);
        o1.x = fmaf(cen[p][4], (float)gs[4], abB.x);
        o1.y = fmaf(cen[p][5], (float)gs[5], abB.y);
        o1.z = fmaf(cen[p][6], (float)gs[6], abB.z);
        o1.w = fmaf(cen[p][7], (float)gs[7], abB.w);
        *(float4*)(ob + 8 * c)     = o0;
        *(float4*)(ob + 8 * c + 4) = o1;
        const float G0 = (float)g3[0], G1 = (float)g3[1], G2 = (float)g3[2], G3 = (float)g3[3];
        float4 w0, w1, w2;
        w0.x = xc.a0.x * G0; w0.y = xc.a0.y * G0; w0.z = xc.a0.z * G0; w0.w = xc.a0.w * G1;
        w1.x = xc.a1.x * G1; w1.y = xc.a1.y * G1; w1.z = xc.a1.z * G2; w1.w = xc.a1.w * G2;
        w2.x = xc.a2.x * G2; w2.y = xc.a2.y * G3; w2.z = xc.a2.z * G3; w2.w = xc.a2.w * G3;
        float* tb = ob + 128 + 12 * c;
        *(float4*)(tb)     = w0;
        *(float4*)(tb + 4) = w1;
        *(float4*)(tb + 8) = w2;
        const float A = (float)g5[0], B = (float)g5[1];
        float2 z0, z1, z2, z3, z4;
        z0.x = xc.b0.x * A; z0.y = xc.b0.y * A;
        z1.x = xc.b1.x * A; z1.y = xc.b1.y * A;
        z2.x = xc.b2.x * A; z2.y = xc.b2.y * B;
        z3.x = xc.b3.x * B; z3.y = xc.b3.y * B;
        z4.x = xc.b4.x * B; z4.y = xc.b4.y * B;
        float* ub = ob + 320 + 10 * c;
        *(float2*)(ub)     = z0;
        *(float2*)(ub + 2) = z1;
        *(float2*)(ub + 4) = z2;
        *(float2*)(ub + 6) = z3;
        *(float2*)(ub + 8) = z4;
        if (p < 3) xc = xn;
    }
}

// Convert W1 (56x224) -> bf16 [64][224] (rows 56..63 zero), W2 (224x56) -> bf16 [224][64] (cols 56..63 zero)
__global__ __launch_bounds__(256) void convert_w(
    const float* __restrict__ W1, const float* __restrict__ W2,
    bf16* __restrict__ W1b, bf16* __restrict__ W2b)
{
    const int t = blockIdx.x * 256 + threadIdx.x;
    if (t < 64 * 224) {
        const int n = t / 224, k = t % 224;
        W1b[t] = (n < 56) ? (bf16)W1[n * 224 + k] : (bf16)0.f;
    } else {
        const int u = t - 64 * 224;       // < 224*64
        const int n = u >> 6, kk = u & 63;
        W2b[u] = (kk < 56) ? (bf16)W2[n * 56 + kk] : (bf16)0.f;
    }
}

extern "C" void kernel_launch(void* const* d_in, const int* in_sizes, int n_in,
                              void* d_out, int out_size, void* d_ws, size_t ws_size,
                              hipStream_t stream) {
    const float* x  = (const float*)d_in[0];
    const float* W1 = (const float*)d_in[1];
    const float* b1 = (const float*)d_in[2];
    const float* W2 = (const float*)d_in[3];
    const float* b2 = (const float*)d_in[4];
    const float* aw = (const float*)d_in[5];
    const float* ab = (const float*)d_in[6];
    bf16* W1b = (bf16*)d_ws;
    bf16* W2b = W1b + 64 * 224;
    const int rows = in_sizes[0] / 480;   // 200000 = 3125 * 64
    convert_w<<<112, 256, 0, stream>>>(W1, W2, W1b, W2b);
    fused<<<rows / 64, 256, 0, stream>>>(x, b1, b2, aw, ab, W1b, W2b, (float*)d_out);
}